// Round 8
// baseline (312.783 us; speedup 1.0000x reference)
//
#include <hip/hip_runtime.h>

#define N_NODES 50000
#define NEG_SLOPE 0.2f

typedef short s8v __attribute__((ext_vector_type(8)));
typedef float f4v __attribute__((ext_vector_type(4)));

// ---- bf16 helpers (RNE) ---------------------------------------------------
__device__ __forceinline__ ushort f2bf(float f) {
  union { float f; unsigned u; } v; v.f = f;
  return (ushort)((v.u + 0x7FFFu + ((v.u >> 16) & 1u)) >> 16);
}
__device__ __forceinline__ float bf2f(ushort h) {
  union { unsigned u; float f; } v; v.u = ((unsigned)h) << 16;
  return v.f;
}

// ---- both weight transposes in one kernel ---------------------------------
// W0 [128][256] -> W0T [256][128]; W1 [256][128] -> W1T [128][256]
__global__ void convT2_kernel(const float* __restrict__ W0, ushort* __restrict__ W0T,
                              const float* __restrict__ W1, ushort* __restrict__ W1T) {
  int i = blockIdx.x * blockDim.x + threadIdx.x;
  if (i < 32768) {
    int r = i >> 8, c = i & 255;           // W0: R=128, C=256
    W0T[c * 128 + r] = f2bf(W0[i]);
  } else {
    int j = i - 32768;
    int r = j >> 7, c = j & 127;           // W1: R=256, C=128
    W1T[c * 256 + r] = f2bf(W1[j]);
  }
}

// ---- MFMA GEMM, 64M x 128N tile + direct-store attention scores -----------
// A: fp32 (AF32) or bf16, [M,K]. BT: bf16 [N,K]. Block owns ALL 128 cols of
// one head -> complete score rows, plain stores (no atomics, no zero-init).
// grid = (N/128, ceil(M/64)) so the 2 consumers of an A-tile are adjacent.
template <int HEADS, bool AF32>
__global__ __launch_bounds__(256) void gemm_mfma(
    const void* __restrict__ Av, const ushort* __restrict__ BT,
    ushort* __restrict__ C, int M, int N, int K,
    const float* __restrict__ a_src, const float* __restrict__ a_dst,
    float* __restrict__ ss, float* __restrict__ sd) {
  __shared__ ushort As[64][136];   // +8 pad: 16B-aligned, 2-way banks (free)
  __shared__ ushort Bs[128][136];
  const int tid = threadIdx.x;
  const int w = tid >> 6, lane = tid & 63;
  const int q = lane >> 4, r16 = lane & 15;
  const int n0 = blockIdx.x * 128, m0 = blockIdx.y * 64;
  f4v acc[8] = {};
  for (int kc = 0; kc < K; kc += 128) {
    // stage A tile 64x128
#pragma unroll
    for (int i = 0; i < 4; ++i) {
      int c = tid + 256 * i;
      int row = c >> 4, ko = (c & 15) * 8;
      int gm = m0 + row;
      s8v va = {};
      if (gm < M) {
        if (AF32) {
          const float* A = (const float*)Av;
          float4 f0 = *reinterpret_cast<const float4*>(&A[(size_t)gm * K + kc + ko]);
          float4 f1 = *reinterpret_cast<const float4*>(&A[(size_t)gm * K + kc + ko + 4]);
          va[0] = (short)f2bf(f0.x); va[1] = (short)f2bf(f0.y);
          va[2] = (short)f2bf(f0.z); va[3] = (short)f2bf(f0.w);
          va[4] = (short)f2bf(f1.x); va[5] = (short)f2bf(f1.y);
          va[6] = (short)f2bf(f1.z); va[7] = (short)f2bf(f1.w);
        } else {
          const ushort* A = (const ushort*)Av;
          va = *reinterpret_cast<const s8v*>(&A[(size_t)gm * K + kc + ko]);
        }
      }
      *reinterpret_cast<s8v*>(&As[row][ko]) = va;
    }
    // stage B tile 128x128
#pragma unroll
    for (int i = 0; i < 8; ++i) {
      int c = tid + 256 * i;
      int row = c >> 4, ko = (c & 15) * 8;
      s8v vb = *reinterpret_cast<const s8v*>(&BT[(size_t)(n0 + row) * K + kc + ko]);
      *reinterpret_cast<s8v*>(&Bs[row][ko]) = vb;
    }
    __syncthreads();
#pragma unroll
    for (int ks = 0; ks < 4; ++ks) {
      s8v af = *reinterpret_cast<const s8v*>(&As[w * 16 + r16][ks * 32 + q * 8]);
#pragma unroll
      for (int nt = 0; nt < 8; ++nt) {
        s8v bf = *reinterpret_cast<const s8v*>(&Bs[nt * 16 + r16][ks * 32 + q * 8]);
        acc[nt] = __builtin_amdgcn_mfma_f32_16x16x32_bf16(af, bf, acc[nt], 0, 0, 0);
      }
    }
    __syncthreads();
  }
  // C store: D row=(lane>>4)*4+reg, col=lane&15
#pragma unroll
  for (int nt = 0; nt < 8; ++nt)
#pragma unroll
    for (int r = 0; r < 4; ++r) {
      int gm = m0 + w * 16 + q * 4 + r;
      if (gm < M) C[(size_t)gm * N + n0 + nt * 16 + r16] = f2bf(acc[nt][r]);
    }
  // scores: block covers the whole head -> exact sums, direct store
  const int head = n0 >> 7;
  float ps[4] = {0.f, 0.f, 0.f, 0.f}, pd[4] = {0.f, 0.f, 0.f, 0.f};
#pragma unroll
  for (int nt = 0; nt < 8; ++nt) {
    int n = n0 + nt * 16 + r16;
    float as = a_src[n], ad = a_dst[n];
#pragma unroll
    for (int r = 0; r < 4; ++r) {
      ps[r] = fmaf(acc[nt][r], as, ps[r]);
      pd[r] = fmaf(acc[nt][r], ad, pd[r]);
    }
  }
#pragma unroll
  for (int off = 1; off < 16; off <<= 1) {
#pragma unroll
    for (int r = 0; r < 4; ++r) {
      ps[r] += __shfl_xor(ps[r], off);
      pd[r] += __shfl_xor(pd[r], off);
    }
  }
  if (r16 == 0) {
#pragma unroll
    for (int r = 0; r < 4; ++r) {
      int gm = m0 + w * 16 + q * 4 + r;
      if (gm < M) {
        ss[gm * HEADS + head] = ps[r];
        sd[gm * HEADS + head] = pd[r];
      }
    }
  }
}

// ------------- CSR build: hist(+rank) -> scan1 -> scan23 -> scatter ---------
__global__ void hist_kernel(const int* __restrict__ ei, int E, int Etot,
                            int* __restrict__ counts, int* __restrict__ rank) {
  int e = blockIdx.x * blockDim.x + threadIdx.x;
  if (e >= Etot) return;
  int d = (e < E) ? ei[E + e] : (e - E);
  rank[e] = atomicAdd(&counts[d], 1);
}

__global__ __launch_bounds__(1024) void scan1_kernel(const int* __restrict__ counts,
                                                     int* __restrict__ partial,
                                                     int* __restrict__ blocksums, int n) {
  __shared__ int tmp[1024];
  int i = blockIdx.x * 1024 + threadIdx.x;
  int v = (i < n) ? counts[i] : 0;
  tmp[threadIdx.x] = v;
  __syncthreads();
  for (int off = 1; off < 1024; off <<= 1) {
    int t = (threadIdx.x >= off) ? tmp[threadIdx.x - off] : 0;
    __syncthreads();
    tmp[threadIdx.x] += t;
    __syncthreads();
  }
  if (i < n) partial[i] = tmp[threadIdx.x];
  if (threadIdx.x == 1023) blocksums[blockIdx.x] = tmp[1023];
}

// fused scan2+scan3: every block re-scans the <=64 block sums in-wave
__global__ void scan23_kernel(const int* __restrict__ partial,
                              const int* __restrict__ blocksums,
                              int* __restrict__ rowptr, int n, int nb) {
  __shared__ int sb[64];
  int t = threadIdx.x;
  if (t < 64) {
    int v = (t < nb) ? blocksums[t] : 0;
#pragma unroll
    for (int off = 1; off < 64; off <<= 1) {
      int u = __shfl_up(v, off);
      if ((t & 63) >= off) v += u;
    }
    sb[t] = v;
  }
  __syncthreads();
  int i = blockIdx.x * blockDim.x + t;
  if (i == 0) rowptr[0] = 0;
  if (i < n) {
    int b = i >> 10;
    int add = (b > 0) ? sb[b - 1] : 0;
    rowptr[i + 1] = partial[i] + add;
  }
}

// scatter: no atomics; ONE 2B random write per edge (dst implicit in pos)
__global__ void scatter_kernel(const int* __restrict__ ei, int E, int Etot,
                               const int* __restrict__ rowptr,
                               const int* __restrict__ rank,
                               ushort* __restrict__ csrS) {
  int e = blockIdx.x * blockDim.x + threadIdx.x;
  if (e >= Etot) return;
  int s, d;
  if (e < E) { s = ei[e]; d = ei[E + e]; } else { s = d = e - E; }
  csrS[rowptr[d] + rank[e]] = (ushort)s;  // src < 50000 < 65536
}

// ---- edge weights, per-dst thread (dst implicit; seq reads/writes) --------
__global__ void ew0_kernel(const ushort* __restrict__ csrS,
                           const int* __restrict__ rowptr,
                           const float* __restrict__ ss, const float* __restrict__ sd,
                           ushort* __restrict__ wbf) {
  int n = blockIdx.x * blockDim.x + threadIdx.x;
  if (n >= N_NODES) return;
  const float sd0 = sd[n * 2], sd1 = sd[n * 2 + 1];
  const int p1 = rowptr[n + 1];
  for (int p = rowptr[n]; p < p1; ++p) {
    int s = csrS[p];
    float e0 = ss[s * 2] + sd0;
    float e1 = ss[s * 2 + 1] + sd1;
    e0 = (e0 > 0.f) ? e0 : NEG_SLOPE * e0;
    e1 = (e1 > 0.f) ? e1 : NEG_SLOPE * e1;
    ushort2 o; o.x = f2bf(__expf(e0)); o.y = f2bf(__expf(e1));
    *reinterpret_cast<ushort2*>(&wbf[p * 2]) = o;
  }
}

__global__ void ew1_kernel(const ushort* __restrict__ csrS,
                           const int* __restrict__ rowptr,
                           const float* __restrict__ ss, const float* __restrict__ sd,
                           ushort* __restrict__ wbf) {
  int n = blockIdx.x * blockDim.x + threadIdx.x;
  if (n >= N_NODES) return;
  const float sdv = sd[n];
  const int p1 = rowptr[n + 1];
  for (int p = rowptr[n]; p < p1; ++p) {
    int s = csrS[p];
    float e = ss[s] + sdv;
    e = (e > 0.f) ? e : NEG_SLOPE * e;
    wbf[p] = f2bf(__expf(e));
  }
}

// ---- layer-0 aggregation: 4 waves/block, one dst-node per wave ------------
__global__ __launch_bounds__(256) void agg0_kernel(
    const ushort* __restrict__ h0,   // [N,256] bf16
    const ushort* __restrict__ wbf,  // [Etot,2] bf16
    const int* __restrict__ rowptr, const ushort* __restrict__ csrS,
    const float* __restrict__ b0, ushort* __restrict__ hE) {
  const int n = blockIdx.x * 4 + (threadIdx.x >> 6);
  const int t = threadIdx.x & 63;
  const int hd = t >> 5;
  float a0 = 0.f, a1 = 0.f, a2 = 0.f, a3 = 0.f, den = 0.f;
  int p = rowptr[n];
  const int p1 = rowptr[n + 1];
  for (; p + 4 <= p1; p += 4) {  // 4 rows in flight per wave
    const int s0 = csrS[p], s1 = csrS[p + 1], s2 = csrS[p + 2], s3 = csrS[p + 3];
    const float w0 = bf2f(wbf[p * 2 + hd]),     w1 = bf2f(wbf[p * 2 + 2 + hd]);
    const float w2 = bf2f(wbf[p * 2 + 4 + hd]), w3 = bf2f(wbf[p * 2 + 6 + hd]);
    const ushort4 v0 = *reinterpret_cast<const ushort4*>(&h0[(size_t)s0 * 256 + t * 4]);
    const ushort4 v1 = *reinterpret_cast<const ushort4*>(&h0[(size_t)s1 * 256 + t * 4]);
    const ushort4 v2 = *reinterpret_cast<const ushort4*>(&h0[(size_t)s2 * 256 + t * 4]);
    const ushort4 v3 = *reinterpret_cast<const ushort4*>(&h0[(size_t)s3 * 256 + t * 4]);
    den += (w0 + w1) + (w2 + w3);
    a0 = fmaf(w0, bf2f(v0.x), a0); a1 = fmaf(w0, bf2f(v0.y), a1);
    a2 = fmaf(w0, bf2f(v0.z), a2); a3 = fmaf(w0, bf2f(v0.w), a3);
    a0 = fmaf(w1, bf2f(v1.x), a0); a1 = fmaf(w1, bf2f(v1.y), a1);
    a2 = fmaf(w1, bf2f(v1.z), a2); a3 = fmaf(w1, bf2f(v1.w), a3);
    a0 = fmaf(w2, bf2f(v2.x), a0); a1 = fmaf(w2, bf2f(v2.y), a1);
    a2 = fmaf(w2, bf2f(v2.z), a2); a3 = fmaf(w2, bf2f(v2.w), a3);
    a0 = fmaf(w3, bf2f(v3.x), a0); a1 = fmaf(w3, bf2f(v3.y), a1);
    a2 = fmaf(w3, bf2f(v3.z), a2); a3 = fmaf(w3, bf2f(v3.w), a3);
  }
  for (; p < p1; ++p) {
    const int s0 = csrS[p];
    const float w0 = bf2f(wbf[p * 2 + hd]);
    const ushort4 v0 = *reinterpret_cast<const ushort4*>(&h0[(size_t)s0 * 256 + t * 4]);
    den += w0;
    a0 = fmaf(w0, bf2f(v0.x), a0); a1 = fmaf(w0, bf2f(v0.y), a1);
    a2 = fmaf(w0, bf2f(v0.z), a2); a3 = fmaf(w0, bf2f(v0.w), a3);
  }
  const float inv = 1.f / den;
  const float4 bv = reinterpret_cast<const float4*>(b0)[t];
  float o[4] = {fmaf(a0, inv, bv.x), fmaf(a1, inv, bv.y),
                fmaf(a2, inv, bv.z), fmaf(a3, inv, bv.w)};
#pragma unroll
  for (int i = 0; i < 4; ++i) o[i] = (o[i] > 0.f) ? o[i] : (__expf(o[i]) - 1.f);
  ushort4 ov; ov.x = f2bf(o[0]); ov.y = f2bf(o[1]); ov.z = f2bf(o[2]); ov.w = f2bf(o[3]);
  *reinterpret_cast<ushort4*>(&hE[(size_t)n * 256 + t * 4]) = ov;
}

// ---- layer-1 aggregation: 4 waves/block, one dst-node per wave ------------
__global__ __launch_bounds__(256) void agg1_kernel(
    const ushort* __restrict__ h1,   // [N,128] bf16
    const ushort* __restrict__ wbf,  // [Etot] bf16
    const int* __restrict__ rowptr, const ushort* __restrict__ csrS,
    const float* __restrict__ b1, const float2* __restrict__ x,
    float2* __restrict__ out) {
  const int n = blockIdx.x * 4 + (threadIdx.x >> 6);
  const int t = threadIdx.x & 63;
  float a0 = 0.f, a1 = 0.f, den = 0.f;
  int p = rowptr[n];
  const int p1 = rowptr[n + 1];
  for (; p + 4 <= p1; p += 4) {
    const int s0 = csrS[p], s1 = csrS[p + 1], s2 = csrS[p + 2], s3 = csrS[p + 3];
    const float w0 = bf2f(wbf[p]), w1 = bf2f(wbf[p + 1]);
    const float w2 = bf2f(wbf[p + 2]), w3 = bf2f(wbf[p + 3]);
    const ushort2 v0 = *reinterpret_cast<const ushort2*>(&h1[(size_t)s0 * 128 + t * 2]);
    const ushort2 v1 = *reinterpret_cast<const ushort2*>(&h1[(size_t)s1 * 128 + t * 2]);
    const ushort2 v2 = *reinterpret_cast<const ushort2*>(&h1[(size_t)s2 * 128 + t * 2]);
    const ushort2 v3 = *reinterpret_cast<const ushort2*>(&h1[(size_t)s3 * 128 + t * 2]);
    den += (w0 + w1) + (w2 + w3);
    a0 = fmaf(w0, bf2f(v0.x), a0); a1 = fmaf(w0, bf2f(v0.y), a1);
    a0 = fmaf(w1, bf2f(v1.x), a0); a1 = fmaf(w1, bf2f(v1.y), a1);
    a0 = fmaf(w2, bf2f(v2.x), a0); a1 = fmaf(w2, bf2f(v2.y), a1);
    a0 = fmaf(w3, bf2f(v3.x), a0); a1 = fmaf(w3, bf2f(v3.y), a1);
  }
  for (; p < p1; ++p) {
    const int s0 = csrS[p];
    const float w0 = bf2f(wbf[p]);
    const ushort2 v0 = *reinterpret_cast<const ushort2*>(&h1[(size_t)s0 * 128 + t * 2]);
    den += w0;
    a0 = fmaf(w0, bf2f(v0.x), a0); a1 = fmaf(w0, bf2f(v0.y), a1);
  }
  const float inv = 1.f / den;
  const float2 bv = reinterpret_cast<const float2*>(b1)[t];
  const float2 xv = x[(size_t)n * 64 + t];
  out[(size_t)n * 64 + t] =
      make_float2(xv.x + fmaf(a0, inv, bv.x), xv.y + fmaf(a1, inv, bv.y));
}

extern "C" void kernel_launch(void* const* d_in, const int* in_sizes, int n_in,
                              void* d_out, int out_size, void* d_ws, size_t ws_size,
                              hipStream_t stream) {
  const float* x      = (const float*)d_in[0];
  const float* W0     = (const float*)d_in[1];
  const float* a_src0 = (const float*)d_in[2];
  const float* a_dst0 = (const float*)d_in[3];
  const float* b0     = (const float*)d_in[4];
  const float* W1     = (const float*)d_in[5];
  const float* a_src1 = (const float*)d_in[6];
  const float* a_dst1 = (const float*)d_in[7];
  const float* b1     = (const float*)d_in[8];
  const int*   ei     = (const int*)d_in[9];
  const int E = in_sizes[9] / 2;
  const int Etot = E + N_NODES;
  float* out = (float*)d_out;
  (void)n_in; (void)out_size; (void)ws_size;

  char* ws = (char*)d_ws;
  size_t off = 0;
  auto alloc = [&](size_t bytes) -> char* {
    char* p = ws + off;
    off += (bytes + 255) & ~(size_t)255;
    return p;
  };
  ushort* h0b  = (ushort*)alloc((size_t)N_NODES * 256 * 2);
  ushort* hEb  = (ushort*)alloc((size_t)N_NODES * 256 * 2);
  ushort* h1b  = (ushort*)alloc((size_t)N_NODES * 128 * 2);
  ushort* W0T  = (ushort*)alloc((size_t)256 * 128 * 2);
  ushort* W1T  = (ushort*)alloc((size_t)128 * 256 * 2);
  int* counts  = (int*)alloc((size_t)N_NODES * 4);      // zero-init below
  float* ss0   = (float*)alloc((size_t)N_NODES * 2 * 4);  // direct-stored
  float* sd0   = (float*)alloc((size_t)N_NODES * 2 * 4);
  float* ss1   = (float*)alloc((size_t)N_NODES * 4);
  float* sd1   = (float*)alloc((size_t)N_NODES * 4);
  int* rowptr  = (int*)alloc((size_t)(N_NODES + 1) * 4);
  int* partial = (int*)alloc((size_t)N_NODES * 4);
  int* bsums   = (int*)alloc((size_t)64 * 4);
  int* rank    = (int*)alloc((size_t)Etot * 4);
  ushort* csrS = (ushort*)alloc((size_t)Etot * 2);
  ushort* wbf0 = (ushort*)alloc((size_t)Etot * 2 * 2);
  ushort* wbf1 = (ushort*)alloc((size_t)Etot * 2);

  hipMemsetAsync(counts, 0, (size_t)N_NODES * 4, stream);

  // ---- prep: weight transposes (one kernel) ----
  convT2_kernel<<<65536 / 256, 256, 0, stream>>>(W0, W0T, W1, W1T);

  // ---- CSR build (shared by both layers) ----
  const int nblk = (N_NODES + 1023) / 1024;  // 49
  hist_kernel<<<(Etot + 255) / 256, 256, 0, stream>>>(ei, E, Etot, counts, rank);
  scan1_kernel<<<nblk, 1024, 0, stream>>>(counts, partial, bsums, N_NODES);
  scan23_kernel<<<(N_NODES + 255) / 256, 256, 0, stream>>>(partial, bsums, rowptr,
                                                           N_NODES, nblk);
  scatter_kernel<<<(Etot + 255) / 256, 256, 0, stream>>>(ei, E, Etot, rowptr, rank, csrS);

  // ---- layer 0 (x converted fp32->bf16 inside gemm staging) ----
  dim3 g0(2, (N_NODES + 63) / 64);
  gemm_mfma<2, true><<<g0, 256, 0, stream>>>(x, W0T, h0b, N_NODES, 256, 128,
                                             a_src0, a_dst0, ss0, sd0);
  ew0_kernel<<<(N_NODES + 255) / 256, 256, 0, stream>>>(csrS, rowptr, ss0, sd0, wbf0);
  agg0_kernel<<<N_NODES / 4, 256, 0, stream>>>(h0b, wbf0, rowptr, csrS, b0, hEb);

  // ---- layer 1 ----
  dim3 g1(1, (N_NODES + 63) / 64);
  gemm_mfma<1, false><<<g1, 256, 0, stream>>>(hEb, W1T, h1b, N_NODES, 128, 256,
                                              a_src1, a_dst1, ss1, sd1);
  ew1_kernel<<<(N_NODES + 255) / 256, 256, 0, stream>>>(csrS, rowptr, ss1, sd1, wbf1);
  agg1_kernel<<<N_NODES / 4, 256, 0, stream>>>(h1b, wbf1, rowptr, csrS, b1,
                                               (const float2*)x, (float2*)out);
}

// Round 10
// 298.299 us; speedup vs baseline: 1.0486x; 1.0486x over previous
//
#include <hip/hip_runtime.h>

#define N_NODES 50000
#define NEG_SLOPE 0.2f

typedef short s8v __attribute__((ext_vector_type(8)));
typedef float f4v __attribute__((ext_vector_type(4)));

// ---- bf16 helpers (RNE) ---------------------------------------------------
__device__ __forceinline__ ushort f2bf(float f) {
  union { float f; unsigned u; } v; v.f = f;
  return (ushort)((v.u + 0x7FFFu + ((v.u >> 16) & 1u)) >> 16);
}
__device__ __forceinline__ float bf2f(ushort h) {
  union { unsigned u; float f; } v; v.u = ((unsigned)h) << 16;
  return v.f;
}

// ---- both weight transposes in one kernel ---------------------------------
__global__ void convT2_kernel(const float* __restrict__ W0, ushort* __restrict__ W0T,
                              const float* __restrict__ W1, ushort* __restrict__ W1T) {
  int i = blockIdx.x * blockDim.x + threadIdx.x;
  if (i < 32768) {
    int r = i >> 8, c = i & 255;           // W0: R=128, C=256
    W0T[c * 128 + r] = f2bf(W0[i]);
  } else {
    int j = i - 32768;
    int r = j >> 7, c = j & 127;           // W1: R=256, C=128
    W1T[c * 256 + r] = f2bf(W1[j]);
  }
}

// ---- MFMA GEMM, 64M x 128N tile + direct-store attention scores -----------
// R8-proven structure. A: fp32 (AF32) or bf16, [M,K]. BT: bf16 [N,K].
// Block owns ALL 128 cols of one head -> exact score rows, plain stores.
template <int HEADS, bool AF32>
__global__ __launch_bounds__(256) void gemm_mfma(
    const void* __restrict__ Av, const ushort* __restrict__ BT,
    ushort* __restrict__ C, int M, int N, int K,
    const float* __restrict__ a_src, const float* __restrict__ a_dst,
    float* __restrict__ ss, float* __restrict__ sd) {
  __shared__ ushort As[64][136];   // +8 pad: 16B-aligned, 2-way banks (free)
  __shared__ ushort Bs[128][136];
  const int tid = threadIdx.x;
  const int w = tid >> 6, lane = tid & 63;
  const int q = lane >> 4, r16 = lane & 15;
  const int n0 = blockIdx.x * 128, m0 = blockIdx.y * 64;
  f4v acc[8] = {};
  for (int kc = 0; kc < K; kc += 128) {
    // stage A tile 64x128
#pragma unroll
    for (int i = 0; i < 4; ++i) {
      int c = tid + 256 * i;
      int row = c >> 4, ko = (c & 15) * 8;
      int gm = m0 + row;
      s8v va = {};
      if (gm < M) {
        if (AF32) {
          const float* A = (const float*)Av;
          float4 f0 = *reinterpret_cast<const float4*>(&A[(size_t)gm * K + kc + ko]);
          float4 f1 = *reinterpret_cast<const float4*>(&A[(size_t)gm * K + kc + ko + 4]);
          va[0] = (short)f2bf(f0.x); va[1] = (short)f2bf(f0.y);
          va[2] = (short)f2bf(f0.z); va[3] = (short)f2bf(f0.w);
          va[4] = (short)f2bf(f1.x); va[5] = (short)f2bf(f1.y);
          va[6] = (short)f2bf(f1.z); va[7] = (short)f2bf(f1.w);
        } else {
          const ushort* A = (const ushort*)Av;
          va = *reinterpret_cast<const s8v*>(&A[(size_t)gm * K + kc + ko]);
        }
      }
      *reinterpret_cast<s8v*>(&As[row][ko]) = va;
    }
    // stage B tile 128x128
#pragma unroll
    for (int i = 0; i < 8; ++i) {
      int c = tid + 256 * i;
      int row = c >> 4, ko = (c & 15) * 8;
      s8v vb = *reinterpret_cast<const s8v*>(&BT[(size_t)(n0 + row) * K + kc + ko]);
      *reinterpret_cast<s8v*>(&Bs[row][ko]) = vb;
    }
    __syncthreads();
#pragma unroll
    for (int ks = 0; ks < 4; ++ks) {
      s8v af = *reinterpret_cast<const s8v*>(&As[w * 16 + r16][ks * 32 + q * 8]);
#pragma unroll
      for (int nt = 0; nt < 8; ++nt) {
        s8v bf = *reinterpret_cast<const s8v*>(&Bs[nt * 16 + r16][ks * 32 + q * 8]);
        acc[nt] = __builtin_amdgcn_mfma_f32_16x16x32_bf16(af, bf, acc[nt], 0, 0, 0);
      }
    }
    __syncthreads();
  }
  // C store: D row=(lane>>4)*4+reg, col=lane&15
#pragma unroll
  for (int nt = 0; nt < 8; ++nt)
#pragma unroll
    for (int r = 0; r < 4; ++r) {
      int gm = m0 + w * 16 + q * 4 + r;
      if (gm < M) C[(size_t)gm * N + n0 + nt * 16 + r16] = f2bf(acc[nt][r]);
    }
  // scores: block covers the whole head -> exact sums, direct store
  const int head = n0 >> 7;
  float ps[4] = {0.f, 0.f, 0.f, 0.f}, pd[4] = {0.f, 0.f, 0.f, 0.f};
#pragma unroll
  for (int nt = 0; nt < 8; ++nt) {
    int n = n0 + nt * 16 + r16;
    float as = a_src[n], ad = a_dst[n];
#pragma unroll
    for (int r = 0; r < 4; ++r) {
      ps[r] = fmaf(acc[nt][r], as, ps[r]);
      pd[r] = fmaf(acc[nt][r], ad, pd[r]);
    }
  }
#pragma unroll
  for (int off = 1; off < 16; off <<= 1) {
#pragma unroll
    for (int r = 0; r < 4; ++r) {
      ps[r] += __shfl_xor(ps[r], off);
      pd[r] += __shfl_xor(pd[r], off);
    }
  }
  if (r16 == 0) {
#pragma unroll
    for (int r = 0; r < 4; ++r) {
      int gm = m0 + w * 16 + q * 4 + r;
      if (gm < M) {
        ss[gm * HEADS + head] = ps[r];
        sd[gm * HEADS + head] = pd[r];
      }
    }
  }
}

// ------------- CSR build: hist(+rank) -> scan1 -> scan23 -> scatter ---------
__global__ void hist_kernel(const int* __restrict__ ei, int E, int Etot,
                            int* __restrict__ counts, int* __restrict__ rank) {
  int e = blockIdx.x * blockDim.x + threadIdx.x;
  if (e >= Etot) return;
  int d = (e < E) ? ei[E + e] : (e - E);
  rank[e] = atomicAdd(&counts[d], 1);
}

__global__ __launch_bounds__(1024) void scan1_kernel(const int* __restrict__ counts,
                                                     int* __restrict__ partial,
                                                     int* __restrict__ blocksums, int n) {
  __shared__ int tmp[1024];
  int i = blockIdx.x * 1024 + threadIdx.x;
  int v = (i < n) ? counts[i] : 0;
  tmp[threadIdx.x] = v;
  __syncthreads();
  for (int off = 1; off < 1024; off <<= 1) {
    int t = (threadIdx.x >= off) ? tmp[threadIdx.x - off] : 0;
    __syncthreads();
    tmp[threadIdx.x] += t;
    __syncthreads();
  }
  if (i < n) partial[i] = tmp[threadIdx.x];
  if (threadIdx.x == 1023) blocksums[blockIdx.x] = tmp[1023];
}

__global__ void scan23_kernel(const int* __restrict__ partial,
                              const int* __restrict__ blocksums,
                              int* __restrict__ rowptr, int n, int nb) {
  __shared__ int sb[64];
  int t = threadIdx.x;
  if (t < 64) {
    int v = (t < nb) ? blocksums[t] : 0;
#pragma unroll
    for (int off = 1; off < 64; off <<= 1) {
      int u = __shfl_up(v, off);
      if ((t & 63) >= off) v += u;
    }
    sb[t] = v;
  }
  __syncthreads();
  int i = blockIdx.x * blockDim.x + t;
  if (i == 0) rowptr[0] = 0;
  if (i < n) {
    int b = i >> 10;
    int add = (b > 0) ? sb[b - 1] : 0;
    rowptr[i + 1] = partial[i] + add;
  }
}

// scatter: no atomics; ONE 4B random write per edge (s | d<<16, both <65536)
__global__ void scatter_kernel(const int* __restrict__ ei, int E, int Etot,
                               const int* __restrict__ rowptr,
                               const int* __restrict__ rank,
                               unsigned* __restrict__ csrSD) {
  int e = blockIdx.x * blockDim.x + threadIdx.x;
  if (e >= Etot) return;
  int s, d;
  if (e < E) { s = ei[e]; d = ei[E + e]; } else { s = d = e - E; }
  csrSD[rowptr[d] + rank[e]] = (unsigned)s | ((unsigned)d << 16);
}

// ---- edge weights, per-edge threads (max parallelism) ---------------------
__global__ void ew0_kernel(const unsigned* __restrict__ csrSD,
                           const float* __restrict__ ss, const float* __restrict__ sd,
                           ushort* __restrict__ wbf, int Etot) {
  int p = blockIdx.x * blockDim.x + threadIdx.x;
  if (p >= Etot) return;
  unsigned v = csrSD[p];
  int s = (int)(v & 0xFFFFu), d = (int)(v >> 16);
  float e0 = ss[s * 2] + sd[d * 2];
  float e1 = ss[s * 2 + 1] + sd[d * 2 + 1];
  e0 = (e0 > 0.f) ? e0 : NEG_SLOPE * e0;
  e1 = (e1 > 0.f) ? e1 : NEG_SLOPE * e1;
  ushort2 o; o.x = f2bf(__expf(e0)); o.y = f2bf(__expf(e1));
  *reinterpret_cast<ushort2*>(&wbf[p * 2]) = o;
}

__global__ void ew1_kernel(const unsigned* __restrict__ csrSD,
                           const float* __restrict__ ss, const float* __restrict__ sd,
                           ushort* __restrict__ wbf, int Etot) {
  int p = blockIdx.x * blockDim.x + threadIdx.x;
  if (p >= Etot) return;
  unsigned v = csrSD[p];
  int s = (int)(v & 0xFFFFu), d = (int)(v >> 16);
  float e = ss[s] + sd[d];
  e = (e > 0.f) ? e : NEG_SLOPE * e;
  wbf[p] = f2bf(__expf(e));
}

// ---- layer-0 aggregation: 4 waves/block, one dst-node per wave ------------
__global__ __launch_bounds__(256) void agg0_kernel(
    const ushort* __restrict__ h0,   // [N,256] bf16
    const ushort* __restrict__ wbf,  // [Etot,2] bf16
    const int* __restrict__ rowptr, const unsigned* __restrict__ csrSD,
    const float* __restrict__ b0, ushort* __restrict__ hE) {
  const int n = blockIdx.x * 4 + (threadIdx.x >> 6);
  const int t = threadIdx.x & 63;
  const int hd = t >> 5;
  float a0 = 0.f, a1 = 0.f, a2 = 0.f, a3 = 0.f, den = 0.f;
  int p = rowptr[n];
  const int p1 = rowptr[n + 1];
  for (; p + 4 <= p1; p += 4) {  // 4 rows in flight per wave
    const int s0 = (int)(csrSD[p] & 0xFFFFu), s1 = (int)(csrSD[p + 1] & 0xFFFFu);
    const int s2 = (int)(csrSD[p + 2] & 0xFFFFu), s3 = (int)(csrSD[p + 3] & 0xFFFFu);
    const float w0 = bf2f(wbf[p * 2 + hd]),     w1 = bf2f(wbf[p * 2 + 2 + hd]);
    const float w2 = bf2f(wbf[p * 2 + 4 + hd]), w3 = bf2f(wbf[p * 2 + 6 + hd]);
    const ushort4 v0 = *reinterpret_cast<const ushort4*>(&h0[(size_t)s0 * 256 + t * 4]);
    const ushort4 v1 = *reinterpret_cast<const ushort4*>(&h0[(size_t)s1 * 256 + t * 4]);
    const ushort4 v2 = *reinterpret_cast<const ushort4*>(&h0[(size_t)s2 * 256 + t * 4]);
    const ushort4 v3 = *reinterpret_cast<const ushort4*>(&h0[(size_t)s3 * 256 + t * 4]);
    den += (w0 + w1) + (w2 + w3);
    a0 = fmaf(w0, bf2f(v0.x), a0); a1 = fmaf(w0, bf2f(v0.y), a1);
    a2 = fmaf(w0, bf2f(v0.z), a2); a3 = fmaf(w0, bf2f(v0.w), a3);
    a0 = fmaf(w1, bf2f(v1.x), a0); a1 = fmaf(w1, bf2f(v1.y), a1);
    a2 = fmaf(w1, bf2f(v1.z), a2); a3 = fmaf(w1, bf2f(v1.w), a3);
    a0 = fmaf(w2, bf2f(v2.x), a0); a1 = fmaf(w2, bf2f(v2.y), a1);
    a2 = fmaf(w2, bf2f(v2.z), a2); a3 = fmaf(w2, bf2f(v2.w), a3);
    a0 = fmaf(w3, bf2f(v3.x), a0); a1 = fmaf(w3, bf2f(v3.y), a1);
    a2 = fmaf(w3, bf2f(v3.z), a2); a3 = fmaf(w3, bf2f(v3.w), a3);
  }
  for (; p < p1; ++p) {
    const int s0 = (int)(csrSD[p] & 0xFFFFu);
    const float w0 = bf2f(wbf[p * 2 + hd]);
    const ushort4 v0 = *reinterpret_cast<const ushort4*>(&h0[(size_t)s0 * 256 + t * 4]);
    den += w0;
    a0 = fmaf(w0, bf2f(v0.x), a0); a1 = fmaf(w0, bf2f(v0.y), a1);
    a2 = fmaf(w0, bf2f(v0.z), a2); a3 = fmaf(w0, bf2f(v0.w), a3);
  }
  const float inv = 1.f / den;
  const float4 bv = reinterpret_cast<const float4*>(b0)[t];
  float o[4] = {fmaf(a0, inv, bv.x), fmaf(a1, inv, bv.y),
                fmaf(a2, inv, bv.z), fmaf(a3, inv, bv.w)};
#pragma unroll
  for (int i = 0; i < 4; ++i) o[i] = (o[i] > 0.f) ? o[i] : (__expf(o[i]) - 1.f);
  ushort4 ov; ov.x = f2bf(o[0]); ov.y = f2bf(o[1]); ov.z = f2bf(o[2]); ov.w = f2bf(o[3]);
  *reinterpret_cast<ushort4*>(&hE[(size_t)n * 256 + t * 4]) = ov;
}

// ---- layer-1 aggregation: 4 waves/block, one dst-node per wave ------------
__global__ __launch_bounds__(256) void agg1_kernel(
    const ushort* __restrict__ h1,   // [N,128] bf16
    const ushort* __restrict__ wbf,  // [Etot] bf16
    const int* __restrict__ rowptr, const unsigned* __restrict__ csrSD,
    const float* __restrict__ b1, const float2* __restrict__ x,
    float2* __restrict__ out) {
  const int n = blockIdx.x * 4 + (threadIdx.x >> 6);
  const int t = threadIdx.x & 63;
  float a0 = 0.f, a1 = 0.f, den = 0.f;
  int p = rowptr[n];
  const int p1 = rowptr[n + 1];
  for (; p + 4 <= p1; p += 4) {
    const int s0 = (int)(csrSD[p] & 0xFFFFu), s1 = (int)(csrSD[p + 1] & 0xFFFFu);
    const int s2 = (int)(csrSD[p + 2] & 0xFFFFu), s3 = (int)(csrSD[p + 3] & 0xFFFFu);
    const float w0 = bf2f(wbf[p]), w1 = bf2f(wbf[p + 1]);
    const float w2 = bf2f(wbf[p + 2]), w3 = bf2f(wbf[p + 3]);
    const ushort2 v0 = *reinterpret_cast<const ushort2*>(&h1[(size_t)s0 * 128 + t * 2]);
    const ushort2 v1 = *reinterpret_cast<const ushort2*>(&h1[(size_t)s1 * 128 + t * 2]);
    const ushort2 v2 = *reinterpret_cast<const ushort2*>(&h1[(size_t)s2 * 128 + t * 2]);
    const ushort2 v3 = *reinterpret_cast<const ushort2*>(&h1[(size_t)s3 * 128 + t * 2]);
    den += (w0 + w1) + (w2 + w3);
    a0 = fmaf(w0, bf2f(v0.x), a0); a1 = fmaf(w0, bf2f(v0.y), a1);
    a0 = fmaf(w1, bf2f(v1.x), a0); a1 = fmaf(w1, bf2f(v1.y), a1);
    a0 = fmaf(w2, bf2f(v2.x), a0); a1 = fmaf(w2, bf2f(v2.y), a1);
    a0 = fmaf(w3, bf2f(v3.x), a0); a1 = fmaf(w3, bf2f(v3.y), a1);
  }
  for (; p < p1; ++p) {
    const int s0 = (int)(csrSD[p] & 0xFFFFu);
    const float w0 = bf2f(wbf[p]);
    const ushort2 v0 = *reinterpret_cast<const ushort2*>(&h1[(size_t)s0 * 128 + t * 2]);
    den += w0;
    a0 = fmaf(w0, bf2f(v0.x), a0); a1 = fmaf(w0, bf2f(v0.y), a1);
  }
  const float inv = 1.f / den;
  const float2 bv = reinterpret_cast<const float2*>(b1)[t];
  const float2 xv = x[(size_t)n * 64 + t];
  out[(size_t)n * 64 + t] =
      make_float2(xv.x + fmaf(a0, inv, bv.x), xv.y + fmaf(a1, inv, bv.y));
}

extern "C" void kernel_launch(void* const* d_in, const int* in_sizes, int n_in,
                              void* d_out, int out_size, void* d_ws, size_t ws_size,
                              hipStream_t stream) {
  const float* x      = (const float*)d_in[0];
  const float* W0     = (const float*)d_in[1];
  const float* a_src0 = (const float*)d_in[2];
  const float* a_dst0 = (const float*)d_in[3];
  const float* b0     = (const float*)d_in[4];
  const float* W1     = (const float*)d_in[5];
  const float* a_src1 = (const float*)d_in[6];
  const float* a_dst1 = (const float*)d_in[7];
  const float* b1     = (const float*)d_in[8];
  const int*   ei     = (const int*)d_in[9];
  const int E = in_sizes[9] / 2;
  const int Etot = E + N_NODES;
  float* out = (float*)d_out;
  (void)n_in; (void)out_size; (void)ws_size;

  char* ws = (char*)d_ws;
  size_t off = 0;
  auto alloc = [&](size_t bytes) -> char* {
    char* p = ws + off;
    off += (bytes + 255) & ~(size_t)255;
    return p;
  };
  ushort* h0b  = (ushort*)alloc((size_t)N_NODES * 256 * 2);
  ushort* hEb  = (ushort*)alloc((size_t)N_NODES * 256 * 2);
  ushort* h1b  = (ushort*)alloc((size_t)N_NODES * 128 * 2);
  ushort* W0T  = (ushort*)alloc((size_t)256 * 128 * 2);
  ushort* W1T  = (ushort*)alloc((size_t)128 * 256 * 2);
  int* counts  = (int*)alloc((size_t)N_NODES * 4);      // zero-init below
  float* ss0   = (float*)alloc((size_t)N_NODES * 2 * 4);  // direct-stored
  float* sd0   = (float*)alloc((size_t)N_NODES * 2 * 4);
  float* ss1   = (float*)alloc((size_t)N_NODES * 4);
  float* sd1   = (float*)alloc((size_t)N_NODES * 4);
  int* rowptr  = (int*)alloc((size_t)(N_NODES + 1) * 4);
  int* partial = (int*)alloc((size_t)N_NODES * 4);
  int* bsums   = (int*)alloc((size_t)64 * 4);
  int* rank    = (int*)alloc((size_t)Etot * 4);
  unsigned* csrSD = (unsigned*)alloc((size_t)Etot * 4);
  ushort* wbf0 = (ushort*)alloc((size_t)Etot * 2 * 2);
  ushort* wbf1 = (ushort*)alloc((size_t)Etot * 2);

  hipMemsetAsync(counts, 0, (size_t)N_NODES * 4, stream);

  // ---- prep: weight transposes (one kernel) ----
  convT2_kernel<<<65536 / 256, 256, 0, stream>>>(W0, W0T, W1, W1T);

  // ---- CSR build (shared by both layers) ----
  const int nblk = (N_NODES + 1023) / 1024;  // 49
  hist_kernel<<<(Etot + 255) / 256, 256, 0, stream>>>(ei, E, Etot, counts, rank);
  scan1_kernel<<<nblk, 1024, 0, stream>>>(counts, partial, bsums, N_NODES);
  scan23_kernel<<<(N_NODES + 255) / 256, 256, 0, stream>>>(partial, bsums, rowptr,
                                                           N_NODES, nblk);
  scatter_kernel<<<(Etot + 255) / 256, 256, 0, stream>>>(ei, E, Etot, rowptr, rank, csrSD);

  // ---- layer 0 (x converted fp32->bf16 inside gemm staging) ----
  dim3 g0(2, (N_NODES + 63) / 64);
  gemm_mfma<2, true><<<g0, 256, 0, stream>>>(x, W0T, h0b, N_NODES, 256, 128,
                                             a_src0, a_dst0, ss0, sd0);
  ew0_kernel<<<(Etot + 255) / 256, 256, 0, stream>>>(csrSD, ss0, sd0, wbf0, Etot);
  agg0_kernel<<<N_NODES / 4, 256, 0, stream>>>(h0b, wbf0, rowptr, csrSD, b0, hEb);

  // ---- layer 1 ----
  dim3 g1(1, (N_NODES + 63) / 64);
  gemm_mfma<1, false><<<g1, 256, 0, stream>>>(hEb, W1T, h1b, N_NODES, 128, 256,
                                              a_src1, a_dst1, ss1, sd1);
  ew1_kernel<<<(Etot + 255) / 256, 256, 0, stream>>>(csrSD, ss1, sd1, wbf1, Etot);
  agg1_kernel<<<N_NODES / 4, 256, 0, stream>>>(h1b, wbf1, rowptr, csrSD, b1,
                                               (const float2*)x, (float2*)out);
}